// Round 3
// baseline (609.517 us; speedup 1.0000x reference)
//
#include <hip/hip_runtime.h>
#include <math.h>

#define CC 128
#define HH 64
#define RBD 8

__device__ __forceinline__ float silu_f(float x) {
    return x / (1.0f + __expf(-x));
}

// ---------------- transpose MLP weights ----------------
__global__ void k_prep(const float* __restrict__ w0, const float* __restrict__ w1,
                       const float* __restrict__ w2, const float* __restrict__ w3,
                       float* __restrict__ w0T, float* __restrict__ w1T,
                       float* __restrict__ w2T, float* __restrict__ w3T) {
    int i = blockIdx.x * blockDim.x + threadIdx.x;
    if (i < 64 * 8) { int m = i / 8, k = i % 8; w0T[i] = w0[k * 64 + m]; }
    if (i < 64 * 64) { int m = i / 64, k = i % 64; w1T[i] = w1[k * 64 + m]; w2T[i] = w2[k * 64 + m]; }
    if (i < 512 * 64) { int j = i / 64, k = i % 64; w3T[i] = w3[k * 512 + j]; }
}

// ---------------- CSR build ----------------
__global__ void k_hist(const int* __restrict__ rcv, int* __restrict__ deg, int E_) {
    int e = blockIdx.x * blockDim.x + threadIdx.x;
    if (e < E_) atomicAdd(&deg[rcv[e]], 1);
}

__global__ __launch_bounds__(1024) void k_scan(const int* __restrict__ deg,
                                               int* __restrict__ off, int N) {
    __shared__ int s[1024];
    int t = threadIdx.x;
    int b = t * 4;
    int a0 = (b + 0 < N) ? deg[b + 0] : 0;
    int a1 = (b + 1 < N) ? deg[b + 1] : 0;
    int a2 = (b + 2 < N) ? deg[b + 2] : 0;
    int a3 = (b + 3 < N) ? deg[b + 3] : 0;
    int part = a0 + a1 + a2 + a3;
    s[t] = part;
    __syncthreads();
    for (int d = 1; d < 1024; d <<= 1) {
        int v = (t >= d) ? s[t - d] : 0;
        __syncthreads();
        s[t] += v;
        __syncthreads();
    }
    int excl = s[t] - part;
    if (b + 0 <= N) off[b + 0] = excl;
    if (b + 1 <= N) off[b + 1] = excl + a0;
    if (b + 2 <= N) off[b + 2] = excl + a0 + a1;
    if (b + 3 <= N) off[b + 3] = excl + a0 + a1 + a2;
}

__global__ void k_scatter(const int* __restrict__ rcv, const int* __restrict__ off,
                          int* __restrict__ cur, int* __restrict__ elist, int E_) {
    int e = blockIdx.x * blockDim.x + threadIdx.x;
    if (e < E_) {
        int r = rcv[e];
        int p = atomicAdd(&cur[r], 1);
        elist[off[r] + p] = e;
    }
}

// ---------------- node linear ----------------
__global__ __launch_bounds__(128) void k_node_lin(
    const float* __restrict__ xs, const float* __restrict__ xv,
    const float* __restrict__ W10, const float* __restrict__ W11,
    float* __restrict__ y0, float* __restrict__ y1, int N) {
    const int d = threadIdx.x;
    const int n0 = blockIdx.x * 4;
    const float inv_c = 0.08838834764831845f;
    float a0[4] = {0.f, 0.f, 0.f, 0.f};
    float av[4][3] = {};
    #pragma unroll 4
    for (int c = 0; c < CC; c++) {
        float w10 = W10[c * CC + d];
        float w11 = W11[c * CC + d];
        #pragma unroll
        for (int n = 0; n < 4; n++) {
            a0[n] += xs[(n0 + n) * CC + c] * w10;
            #pragma unroll
            for (int i = 0; i < 3; i++)
                av[n][i] += xv[((n0 + n) * CC + c) * 3 + i] * w11;
        }
    }
    #pragma unroll
    for (int n = 0; n < 4; n++) {
        y0[(n0 + n) * CC + d] = a0[n] * inv_c;
        #pragma unroll
        for (int i = 0; i < 3; i++)
            y1[((n0 + n) * CC + d) * 3 + i] = av[n][i] * inv_c;
    }
}

// ---------------- per-edge radial MLP -> h2 ----------------
__device__ __forceinline__ void layer64(const float4* a, float4* b,
                                        const float* __restrict__ W) {
    #pragma unroll
    for (int m = 0; m < 16; m++) {
        float s0 = 0.f, s1 = 0.f, s2 = 0.f, s3 = 0.f;
        const float* w0p = W + (4 * m + 0) * 64;
        const float* w1p = W + (4 * m + 1) * 64;
        const float* w2p = W + (4 * m + 2) * 64;
        const float* w3p = W + (4 * m + 3) * 64;
        #pragma unroll
        for (int k = 0; k < 16; k++) {
            float4 av = a[k];
            s0 += av.x * w0p[4 * k + 0] + av.y * w0p[4 * k + 1] + av.z * w0p[4 * k + 2] + av.w * w0p[4 * k + 3];
            s1 += av.x * w1p[4 * k + 0] + av.y * w1p[4 * k + 1] + av.z * w1p[4 * k + 2] + av.w * w1p[4 * k + 3];
            s2 += av.x * w2p[4 * k + 0] + av.y * w2p[4 * k + 1] + av.z * w2p[4 * k + 2] + av.w * w2p[4 * k + 3];
            s3 += av.x * w3p[4 * k + 0] + av.y * w3p[4 * k + 1] + av.z * w3p[4 * k + 2] + av.w * w3p[4 * k + 3];
        }
        b[m] = make_float4(silu_f(s0), silu_f(s1), silu_f(s2), silu_f(s3));
    }
}

__global__ void k_mlp(const float* __restrict__ rb,
                      const float* __restrict__ w0T, const float* __restrict__ w1T,
                      const float* __restrict__ w2T,
                      float* __restrict__ h2, int E_) {
    int e = blockIdx.x * blockDim.x + threadIdx.x;
    if (e >= E_) return;

    float rbv[RBD];
    #pragma unroll
    for (int k = 0; k < RBD; k++) rbv[k] = rb[e * RBD + k];

    float4 a[16], b[16];
    // layer 0: 8 -> 64
    #pragma unroll
    for (int m = 0; m < 16; m++) {
        float s0 = 0.f, s1 = 0.f, s2 = 0.f, s3 = 0.f;
        #pragma unroll
        for (int k = 0; k < RBD; k++) {
            float rv = rbv[k];
            s0 += rv * w0T[(4 * m + 0) * RBD + k];
            s1 += rv * w0T[(4 * m + 1) * RBD + k];
            s2 += rv * w0T[(4 * m + 2) * RBD + k];
            s3 += rv * w0T[(4 * m + 3) * RBD + k];
        }
        a[m] = make_float4(silu_f(s0), silu_f(s1), silu_f(s2), silu_f(s3));
    }
    layer64(a, b, w1T);   // layer 1
    layer64(b, a, w2T);   // layer 2 -> a holds h2
    float4* out = (float4*)(h2 + (size_t)e * HH);
    #pragma unroll
    for (int q = 0; q < 16; q++) out[q] = a[q];
}

// ---------------- CSR gather: block = node, thread = w3 output column ----------------
// w3 column held in NAMED float4 registers so the compiler cannot demote it.
__global__ __launch_bounds__(512, 1) void k_gather(
    const int* __restrict__ off, const int* __restrict__ elist,
    const int* __restrict__ snd, const float* __restrict__ evec,
    const float* __restrict__ h2, const float* __restrict__ w3T,
    const float* __restrict__ y0, const float* __restrict__ y1,
    float* __restrict__ agg_s, float* __restrict__ agg_v) {
    const int r = blockIdx.x;
    const int tid = threadIdx.x;
    const int part = tid >> 7;   // 0..3, wave-uniform
    const int c = tid & 127;

    // this thread's w3 column -> 16 named float4 registers
    const float4* wp = (const float4*)(w3T + (size_t)tid * 64);
    const float4 w00 = wp[0],  w01 = wp[1],  w02 = wp[2],  w03 = wp[3];
    const float4 w04 = wp[4],  w05 = wp[5],  w06 = wp[6],  w07 = wp[7];
    const float4 w08 = wp[8],  w09 = wp[9],  w10 = wp[10], w11 = wp[11];
    const float4 w12 = wp[12], w13 = wp[13], w14 = wp[14], w15 = wp[15];

    const int start = off[r];
    const int end = off[r + 1];

    float acc0 = 0.f, acc1 = 0.f, acc2 = 0.f;
    const float SQ3 = 1.7320508075688772f;

    #pragma unroll 2
    for (int j = start; j < end; j++) {
        int e = elist[j];
        e = __builtin_amdgcn_readfirstlane(e);
        int s = snd[e];
        s = __builtin_amdgcn_readfirstlane(s);

        float e0 = evec[(size_t)e * 3 + 0];
        float e1 = evec[(size_t)e * 3 + 1];
        float e2 = evec[(size_t)e * 3 + 2];
        float rn = sqrtf(e0 * e0 + e1 * e1 + e2 * e2);
        float inv = 1.0f / fmaxf(rn, 1e-12f);
        float ux = e0 * inv, uy = e1 * inv, uz = e2 * inv;

        // dot(h2[e], w-column) — h2 loads are wave-uniform (scalar broadcast)
        const float4* __restrict__ hp = (const float4*)(h2 + ((size_t)e << 6));
        float ws0, ws1, ws2, ws3;
        {
            float4 h;
            h = hp[0];  ws0  = h.x * w00.x; ws1  = h.y * w00.y; ws2  = h.z * w00.z; ws3  = h.w * w00.w;
            h = hp[1];  ws0 += h.x * w01.x; ws1 += h.y * w01.y; ws2 += h.z * w01.z; ws3 += h.w * w01.w;
            h = hp[2];  ws0 += h.x * w02.x; ws1 += h.y * w02.y; ws2 += h.z * w02.z; ws3 += h.w * w02.w;
            h = hp[3];  ws0 += h.x * w03.x; ws1 += h.y * w03.y; ws2 += h.z * w03.z; ws3 += h.w * w03.w;
            h = hp[4];  ws0 += h.x * w04.x; ws1 += h.y * w04.y; ws2 += h.z * w04.z; ws3 += h.w * w04.w;
            h = hp[5];  ws0 += h.x * w05.x; ws1 += h.y * w05.y; ws2 += h.z * w05.z; ws3 += h.w * w05.w;
            h = hp[6];  ws0 += h.x * w06.x; ws1 += h.y * w06.y; ws2 += h.z * w06.z; ws3 += h.w * w06.w;
            h = hp[7];  ws0 += h.x * w07.x; ws1 += h.y * w07.y; ws2 += h.z * w07.z; ws3 += h.w * w07.w;
            h = hp[8];  ws0 += h.x * w08.x; ws1 += h.y * w08.y; ws2 += h.z * w08.z; ws3 += h.w * w08.w;
            h = hp[9];  ws0 += h.x * w09.x; ws1 += h.y * w09.y; ws2 += h.z * w09.z; ws3 += h.w * w09.w;
            h = hp[10]; ws0 += h.x * w10.x; ws1 += h.y * w10.y; ws2 += h.z * w10.z; ws3 += h.w * w10.w;
            h = hp[11]; ws0 += h.x * w11.x; ws1 += h.y * w11.y; ws2 += h.z * w11.z; ws3 += h.w * w11.w;
            h = hp[12]; ws0 += h.x * w12.x; ws1 += h.y * w12.y; ws2 += h.z * w12.z; ws3 += h.w * w12.w;
            h = hp[13]; ws0 += h.x * w13.x; ws1 += h.y * w13.y; ws2 += h.z * w13.z; ws3 += h.w * w13.w;
            h = hp[14]; ws0 += h.x * w14.x; ws1 += h.y * w14.y; ws2 += h.z * w14.z; ws3 += h.w * w14.w;
            h = hp[15]; ws0 += h.x * w15.x; ws1 += h.y * w15.y; ws2 += h.z * w15.z; ws3 += h.w * w15.w;
        }
        float wsum = (ws0 + ws1) + (ws2 + ws3);

        if (part == 0) {
            float f = y0[(size_t)s * CC + c];
            acc0 += f * wsum;
        } else if (part == 1) {
            const float* yp = y1 + ((size_t)s * CC + c) * 3;
            float f = yp[0] * ux + yp[1] * uy + yp[2] * uz;
            acc0 += f * wsum;
        } else if (part == 2) {
            float f = y0[(size_t)s * CC + c];
            float bb = f * wsum * SQ3;
            acc0 += bb * ux; acc1 += bb * uy; acc2 += bb * uz;
        } else {
            const float* yp = y1 + ((size_t)s * CC + c) * 3;
            acc0 += yp[0] * wsum; acc1 += yp[1] * wsum; acc2 += yp[2] * wsum;
        }
    }

    if (part == 0) {
        agg_s[(size_t)r * 2 * CC + c] = acc0;
    } else if (part == 1) {
        agg_s[(size_t)r * 2 * CC + CC + c] = acc0;
    } else if (part == 2) {
        float* o = agg_v + ((size_t)r * 2 * CC + c) * 3;
        o[0] = acc0; o[1] = acc1; o[2] = acc2;
    } else {
        float* o = agg_v + ((size_t)r * 2 * CC + CC + c) * 3;
        o[0] = acc0; o[1] = acc1; o[2] = acc2;
    }
}

// ---------------- node output ----------------
__global__ __launch_bounds__(256) void k_node_out(
    const float* __restrict__ agg_s, const float* __restrict__ agg_v,
    const float* __restrict__ xs, const float* __restrict__ xv,
    const float* __restrict__ W20, const float* __restrict__ W21,
    const float* __restrict__ Wsk0, const float* __restrict__ Wsk1,
    const int* __restrict__ species,
    float* __restrict__ out, int N) {
    const int tid = threadIdx.x;
    const int n0 = blockIdx.x * 4;

    __shared__ float as_l[4 * 256];
    __shared__ float av_l[4 * 768];
    __shared__ float xs_l[4 * 128];
    __shared__ float xv_l[4 * 384];
    __shared__ float s_l[4 * 256];

    for (int i = tid; i < 4 * 256; i += 256) as_l[i] = agg_s[(size_t)n0 * 256 + i];
    for (int i = tid; i < 4 * 768; i += 256) av_l[i] = agg_v[(size_t)n0 * 768 + i];
    for (int i = tid; i < 4 * 128; i += 256) xs_l[i] = xs[(size_t)n0 * 128 + i];
    for (int i = tid; i < 4 * 384; i += 256) xv_l[i] = xv[(size_t)n0 * 384 + i];
    int sp[4];
    #pragma unroll
    for (int n = 0; n < 4; n++) sp[n] = species[n0 + n];
    __syncthreads();

    const float k_mat = 0.17677669529663687f * 0.0625f; // inv_nb * inv_2c
    const float inv_c = 0.08838834764831845f;

    {
        const int d = tid;
        float am[4] = {0.f, 0.f, 0.f, 0.f};
        for (int cc = 0; cc < 256; cc++) {
            float w = W20[cc * 256 + d];
            #pragma unroll
            for (int n = 0; n < 4; n++) am[n] += as_l[n * 256 + cc] * w;
        }
        float ak[4] = {0.f, 0.f, 0.f, 0.f};
        for (int cc = 0; cc < 128; cc++) {
            #pragma unroll
            for (int n = 0; n < 4; n++) {
                float w = Wsk0[((size_t)sp[n] * 128 + cc) * 256 + d];
                ak[n] += xs_l[n * 128 + cc] * w;
            }
        }
        #pragma unroll
        for (int n = 0; n < 4; n++) s_l[n * 256 + d] = am[n] * k_mat + ak[n] * inv_c;
    }
    __syncthreads();

    if (tid < 128) {
        #pragma unroll
        for (int n = 0; n < 4; n++)
            out[(size_t)(n0 + n) * 512 + tid] = silu_f(s_l[n * 256 + tid]);
    }

    {
        const int d = tid & 127;
        const int half = tid >> 7;
        int spB[2];
        #pragma unroll
        for (int nn = 0; nn < 2; nn++) spB[nn] = species[n0 + half * 2 + nn];

        float am[2][3] = {};
        for (int cc = 0; cc < 256; cc++) {
            float w = W21[cc * 128 + d];
            #pragma unroll
            for (int nn = 0; nn < 2; nn++) {
                int n = half * 2 + nn;
                #pragma unroll
                for (int i = 0; i < 3; i++) am[nn][i] += av_l[n * 768 + cc * 3 + i] * w;
            }
        }
        float ak[2][3] = {};
        for (int cc = 0; cc < 128; cc++) {
            #pragma unroll
            for (int nn = 0; nn < 2; nn++) {
                int n = half * 2 + nn;
                float w = Wsk1[((size_t)spB[nn] * 128 + cc) * 128 + d];
                #pragma unroll
                for (int i = 0; i < 3; i++) ak[nn][i] += xv_l[n * 384 + cc * 3 + i] * w;
            }
        }
        #pragma unroll
        for (int nn = 0; nn < 2; nn++) {
            int n = half * 2 + nn;
            float g = silu_f(s_l[n * 256 + 128 + d]);
            #pragma unroll
            for (int i = 0; i < 3; i++)
                out[(size_t)(n0 + n) * 512 + 128 + d * 3 + i] =
                    (am[nn][i] * k_mat + ak[nn][i] * inv_c) * g;
        }
    }
}

extern "C" void kernel_launch(void* const* d_in, const int* in_sizes, int n_in,
                              void* d_out, int out_size, void* d_ws, size_t ws_size,
                              hipStream_t stream) {
    const float* xs   = (const float*)d_in[0];
    const float* xv   = (const float*)d_in[1];
    const float* evec = (const float*)d_in[2];
    const float* rb   = (const float*)d_in[3];
    const float* W10  = (const float*)d_in[4];
    const float* W11  = (const float*)d_in[5];
    const float* w0   = (const float*)d_in[6];
    const float* w1   = (const float*)d_in[7];
    const float* w2   = (const float*)d_in[8];
    const float* w3   = (const float*)d_in[9];
    const float* W20  = (const float*)d_in[10];
    const float* W21  = (const float*)d_in[11];
    const float* Wsk0 = (const float*)d_in[12];
    const float* Wsk1 = (const float*)d_in[13];
    const int* species = (const int*)d_in[14];
    const int* snd = (const int*)d_in[15];
    const int* rcv = (const int*)d_in[16];

    const int N = in_sizes[0] / CC;   // 4000
    const int E = in_sizes[2] / 3;    // 128000

    float* ws   = (float*)d_ws;
    float* y0   = ws;
    float* y1   = y0 + (size_t)N * CC;
    float* aggs = y1 + (size_t)N * CC * 3;
    float* aggv = aggs + (size_t)N * 2 * CC;
    float* w0T  = aggv + (size_t)N * 2 * CC * 3;
    float* w1T  = w0T + 64 * 8;
    float* w2T  = w1T + 64 * 64;
    float* w3T  = w2T + 64 * 64;
    float* h2   = w3T + 512 * 64;
    int*   deg  = (int*)(h2 + (size_t)E * HH);
    int*   cur  = deg + 4096;
    int*   off  = cur + 4096;
    int*   elist = off + 4160;

    hipMemsetAsync(deg, 0, 2 * 4096 * sizeof(int), stream);
    hipLaunchKernelGGL(k_hist, dim3((E + 255) / 256), dim3(256), 0, stream, rcv, deg, E);
    hipLaunchKernelGGL(k_scan, dim3(1), dim3(1024), 0, stream, deg, off, N);
    hipLaunchKernelGGL(k_scatter, dim3((E + 255) / 256), dim3(256), 0, stream,
                       rcv, off, cur, elist, E);
    hipLaunchKernelGGL(k_prep, dim3(128), dim3(256), 0, stream,
                       w0, w1, w2, w3, w0T, w1T, w2T, w3T);
    hipLaunchKernelGGL(k_node_lin, dim3(N / 4), dim3(128), 0, stream,
                       xs, xv, W10, W11, y0, y1, N);
    hipLaunchKernelGGL(k_mlp, dim3((E + 255) / 256), dim3(256), 0, stream,
                       rb, w0T, w1T, w2T, h2, E);
    hipLaunchKernelGGL(k_gather, dim3(N), dim3(512), 0, stream,
                       off, elist, snd, evec, h2, w3T, y0, y1, aggs, aggv);
    hipLaunchKernelGGL(k_node_out, dim3(N / 4), dim3(256), 0, stream,
                       aggs, aggv, xs, xv, W20, W21, Wsk0, Wsk1, species,
                       (float*)d_out, N);
}